// Round 5
// baseline (33033.356 us; speedup 1.0000x reference)
//
#include <hip/hip_runtime.h>
#include <hip/hip_cooperative_groups.h>
#include <math.h>

namespace cg = cooperative_groups;

// B=128, S=L=128, H=512, 3H=1536, T=127 steps, SS=100
//
// ws layout (floats):
//   P      [16384][512]     8,388,608   inst_proj rows m=b*128+s
//   WA_s   [256][512][8]    1,048,576   per-A-WG: j={g0c0,g0c1,g1c0,g1c1,g2c0,g2c1,pad,pad}, c0=wg*2
//   WU_s   [128][512][4]      262,144   per-U-WG: cols c0..c0+3, c0=wg*4
//   WD_s   [256][1024][8]   2,097,152   per-D-WG: same j-layout as WA_s, c0=wg*2; K=1024
//                                        (k<512: Wh2^T, k>=512: Wi2[:,512:]^T)
//   xselT  [256][128]          32,768
//   A1f    [1536][2]            3,072   Wi1 @ Wr fold
//   A2f    [1536][2]            3,072
//   c1f    [1536]               1,536
//   c2f    [1536]               1,536
//   h1T    [2][512][128]      131,072   ring slot t&1
//   vstack [2][1024][128]     262,144   rows 0-511 h2, 512-1023 ctx
//   uT     [2][512][128]      131,072
// total 12,362,752 floats = 47.2 MiB

__device__ __forceinline__ float sigm(float x){ return 1.0f/(1.0f+__expf(-x)); }
__device__ __forceinline__ float tanh_(float x){ float e=__expf(2.0f*x); return 1.0f-2.0f/(e+1.0f); }

// ===========================================================================
// prep: P GEMM, weight slicing, input-fold, xselT, zero-init.  grid 2057 x 256
// ===========================================================================
__global__ __launch_bounds__(256)
void prep_kernel(const float* __restrict__ instance, const int* __restrict__ solution,
                 const float* __restrict__ Hst, const float* __restrict__ Wr,
                 const float* __restrict__ br, const float* __restrict__ Wi1,
                 const float* __restrict__ bi1, const float* __restrict__ Wh1,
                 const float* __restrict__ Wa, const float* __restrict__ Ua,
                 const float* __restrict__ Wi2, const float* __restrict__ Wh2,
                 const float* __restrict__ bi2,
                 float* __restrict__ P, float* __restrict__ WAs, float* __restrict__ WUs,
                 float* __restrict__ WDs, float* __restrict__ xselT,
                 float* __restrict__ A1f, float* __restrict__ A2f,
                 float* __restrict__ c1f, float* __restrict__ c2f,
                 float* __restrict__ h1T, float* __restrict__ vstack)
{
  const int w = blockIdx.x, t = threadIdx.x;
  __shared__ float smem[6656];

  if (w < 1024) {
    // ---- P[m][h] = sum_k Hst[m][k] * Wa[h][k]; tile 128m x 64h, k-tiles of 32
    const int m0 = (w >> 3) * 128, h0 = (w & 7) * 64;
    const int hl = t & 15, mseg = t >> 4;
    float acc[4][8];
#pragma unroll
    for (int i = 0; i < 4; ++i)
#pragma unroll
      for (int r = 0; r < 8; ++r) acc[i][r] = 0.f;
    for (int kt = 0; kt < 16; ++kt) {
      { int row = t >> 1, cb = (t & 1) * 16;
        const float4* sp = (const float4*)(Hst + (size_t)(m0 + row) * 512 + kt * 32 + cb);
        float4 q0 = sp[0], q1 = sp[1], q2 = sp[2], q3 = sp[3];
        float vals[16] = {q0.x,q0.y,q0.z,q0.w,q1.x,q1.y,q1.z,q1.w,
                          q2.x,q2.y,q2.z,q2.w,q3.x,q3.y,q3.z,q3.w};
#pragma unroll
        for (int i = 0; i < 16; ++i) smem[(cb + i) * 136 + row] = vals[i]; }
      { int row = t >> 2, cb = (t & 3) * 8;
        const float4* sp = (const float4*)(Wa + (size_t)(h0 + row) * 512 + kt * 32 + cb);
        float4 q0 = sp[0], q1 = sp[1];
        float vals[8] = {q0.x,q0.y,q0.z,q0.w,q1.x,q1.y,q1.z,q1.w};
#pragma unroll
        for (int i = 0; i < 8; ++i) smem[4352 + (cb + i) * 72 + row] = vals[i]; }
      __syncthreads();
#pragma unroll 8
      for (int kk = 0; kk < 32; ++kk) {
        float4 wv = *(const float4*)&smem[4352 + kk * 72 + hl * 4];
        float4 ha = *(const float4*)&smem[kk * 136 + mseg * 8];
        float4 hb = *(const float4*)&smem[kk * 136 + mseg * 8 + 4];
        float wv_[4] = {wv.x, wv.y, wv.z, wv.w};
        float hv_[8] = {ha.x, ha.y, ha.z, ha.w, hb.x, hb.y, hb.z, hb.w};
#pragma unroll
        for (int i = 0; i < 4; ++i)
#pragma unroll
          for (int r = 0; r < 8; ++r) acc[i][r] += wv_[i] * hv_[r];
      }
      __syncthreads();
    }
#pragma unroll
    for (int r = 0; r < 8; ++r) {
      float4 st = {acc[0][r], acc[1][r], acc[2][r], acc[3][r]};
      *(float4*)&P[(size_t)(m0 + mseg * 8 + r) * 512 + h0 + hl * 4] = st;
    }

  } else if (w < 1216) {
    // ---- WA_s slice: 1536x512 elements of Wh1
    for (int i = 0; i < 16; ++i) {
      int e = (w - 1024) * 4096 + i * 256 + t;
      int fc = e >> 9, k = e & 511;
      int g = fc >> 9, c = fc & 511;
      int wg = c >> 1, j = g * 2 + (c & 1);
      WAs[((size_t)wg * 512 + k) * 8 + j] = Wh1[(size_t)fc * 512 + k];
    }
  } else if (w < 1280) {
    // ---- WU_s slice: 512x512 of Ua
    for (int i = 0; i < 16; ++i) {
      int e = (w - 1216) * 4096 + i * 256 + t;
      int c = e >> 9, k = e & 511;
      int wg = c >> 2, j = c & 3;
      WUs[((size_t)wg * 512 + k) * 4 + j] = Ua[(size_t)c * 512 + k];
    }
  } else if (w < 1664) {
    // ---- WD_s slice: 1536 x 1024 (Wh2 | Wi2 ctx half), j-layout like WA_s
    for (int i = 0; i < 16; ++i) {
      int e = (w - 1280) * 4096 + i * 256 + t;
      int fc = e >> 10, k = e & 1023;
      int g = fc >> 9, c = fc & 511;
      int wg = c >> 1, j = g * 2 + (c & 1);
      float src = (k < 512) ? Wh2[(size_t)fc * 512 + k]
                            : Wi2[(size_t)fc * 1024 + 512 + (k - 512)];
      WDs[((size_t)wg * 1024 + k) * 8 + j] = src;
    }
  } else if (w < 2048) {
    // ---- fold: A1f/c1f from Wi1, A2f/c2f from Wi2[:, :512]; one j per wave
    const int wf = w - 1664, wv = t >> 6, lane = t & 63;
    const int j = wf * 4 + wv;
    const float4* w1p = (const float4*)(Wi1 + (size_t)j * 512 + lane * 8);
    const float4* w2p = (const float4*)(Wi2 + (size_t)j * 1024 + lane * 8);
    const float4* wrp = (const float4*)(Wr + lane * 16);
    const float4* brp = (const float4*)(br + lane * 8);
    float4 u0 = w1p[0], u1 = w1p[1], v0 = w2p[0], v1 = w2p[1];
    float4 r0 = wrp[0], r1 = wrp[1], r2 = wrp[2], r3 = wrp[3];
    float4 bb0 = brp[0], bb1 = brp[1];
    float w1a[8] = {u0.x,u0.y,u0.z,u0.w,u1.x,u1.y,u1.z,u1.w};
    float w2a[8] = {v0.x,v0.y,v0.z,v0.w,v1.x,v1.y,v1.z,v1.w};
    float wr0[8] = {r0.x,r0.z,r1.x,r1.z,r2.x,r2.z,r3.x,r3.z};
    float wr1[8] = {r0.y,r0.w,r1.y,r1.w,r2.y,r2.w,r3.y,r3.w};
    float bra[8] = {bb0.x,bb0.y,bb0.z,bb0.w,bb1.x,bb1.y,bb1.z,bb1.w};
    float a0=0,a1=0,cc=0,b0=0,b1=0,cc2=0;
#pragma unroll
    for (int i = 0; i < 8; ++i) {
      a0 += w1a[i]*wr0[i]; a1 += w1a[i]*wr1[i]; cc  += w1a[i]*bra[i];
      b0 += w2a[i]*wr0[i]; b1 += w2a[i]*wr1[i]; cc2 += w2a[i]*bra[i];
    }
#pragma unroll
    for (int off = 32; off; off >>= 1) {
      a0 += __shfl_xor(a0, off); a1 += __shfl_xor(a1, off); cc  += __shfl_xor(cc, off);
      b0 += __shfl_xor(b0, off); b1 += __shfl_xor(b1, off); cc2 += __shfl_xor(cc2, off);
    }
    if (lane == 0) {
      A1f[j*2] = a0; A1f[j*2+1] = a1; c1f[j] = cc + bi1[j];
      A2f[j*2] = b0; A2f[j*2+1] = b1; c2f[j] = cc2 + bi2[j];
    }
  } else if (w == 2048) {
    for (int o = t; o < 32768; o += 256) {
      int b = o & 127, r = o >> 7, d = r & 1, l = r >> 1;
      int sel = solution[b * 128 + l];
      xselT[o] = instance[(size_t)(b * 128 + sel) * 2 + d];
    }
  } else {
    // ---- zero h1T slot1 and vstack slot0 rows 0..511 (states at t=-1)
    const int wz = w - 2049;
    for (int i = 0; i < 32; ++i) {
      int idx = wz * 8192 + i * 256 + t;
      h1T[65536 + idx] = 0.f;
      vstack[idx] = 0.f;
    }
  }
}

// ===========================================================================
// One pipeline round. Round k: A(t=k) U(k-1) B(k-2) D(k-3).
// grid 768 x 256: A [0,256) 2col  U [256,384) 4col  B [384,512) 1b  D [512,768) 2col
// ===========================================================================
__device__ __forceinline__ void round_body(
    int k, int w, int t, int wv, int lane, float* lds,
    const float* __restrict__ Hst, const float* __restrict__ bh1,
    const float* __restrict__ vvec, const float* __restrict__ bh2,
    const float* __restrict__ P, const float* __restrict__ WAs,
    const float* __restrict__ WUs, const float* __restrict__ WDs,
    const float* __restrict__ xselT, const float* __restrict__ A1f,
    const float* __restrict__ A2f, const float* __restrict__ c1f,
    const float* __restrict__ c2f,
    float* __restrict__ h1T, float* __restrict__ vstack, float* __restrict__ uT)
{
  if (w < 256) {
    // ---- A: GRU1. 2 c-cols per WG, k-split 4 waves x 128
    const int tA = k;
    if (tA <= 126) {
      const int slotW = tA & 1, slotR = slotW ^ 1;
      const float* hp = h1T + slotR * 65536 + (wv * 128) * 128 + lane * 2;
      const float4* wp = (const float4*)(WAs + ((size_t)w * 512 + wv * 128) * 8);
      float acc[12];
#pragma unroll
      for (int i = 0; i < 12; ++i) acc[i] = 0.f;
#pragma unroll 4
      for (int kk = 0; kk < 128; ++kk) {
        float2 hv = *(const float2*)(hp + kk * 128);
        float4 wa = wp[kk * 2], wb = wp[kk * 2 + 1];
        acc[0] += hv.x*wa.x; acc[1]  += hv.y*wa.x;
        acc[2] += hv.x*wa.y; acc[3]  += hv.y*wa.y;
        acc[4] += hv.x*wa.z; acc[5]  += hv.y*wa.z;
        acc[6] += hv.x*wa.w; acc[7]  += hv.y*wa.w;
        acc[8] += hv.x*wb.x; acc[9]  += hv.y*wb.x;
        acc[10]+= hv.x*wb.y; acc[11] += hv.y*wb.y;
      }
#pragma unroll
      for (int i = 0; i < 12; ++i) lds[wv * 768 + i * 64 + lane] = acc[i];
      __syncthreads();
      { int b = t & 127, ci = t >> 7, l = b >> 1, bs = b & 1;
        float gr = 0, gz = 0, gn = 0;
#pragma unroll
        for (int w2 = 0; w2 < 4; ++w2) {
          gr += lds[w2 * 768 + (    ci * 2 + bs) * 64 + l];
          gz += lds[w2 * 768 + (4 + ci * 2 + bs) * 64 + l];
          gn += lds[w2 * 768 + (8 + ci * 2 + bs) * 64 + l];
        }
        int c = w * 2 + ci;
        float x0 = xselT[(tA * 2) * 128 + b], x1 = xselT[(tA * 2 + 1) * 128 + b];
        float ir  = A1f[c*2]*x0        + A1f[c*2+1]*x1        + c1f[c];
        float iz  = A1f[(c+512)*2]*x0  + A1f[(c+512)*2+1]*x1  + c1f[c+512];
        float in_ = A1f[(c+1024)*2]*x0 + A1f[(c+1024)*2+1]*x1 + c1f[c+1024];
        float r = sigm(ir + gr + bh1[c]);
        float z = sigm(iz + gz + bh1[c + 512]);
        float n = tanh_(in_ + r * (gn + bh1[c + 1024]));
        float hpv = h1T[slotR * 65536 + c * 128 + b];
        h1T[slotW * 65536 + c * 128 + b] = (1.f - z) * n + z * hpv;
      }
      __syncthreads();
    }
  } else if (w < 384) {
    // ---- U: u = h1(t) @ Ua^T. 4 c-cols per WG
    const int tU = k - 1;
    if (tU >= 0 && tU <= 126) {
      const int slot = tU & 1;
      const float* hp = h1T + slot * 65536 + (wv * 128) * 128 + lane * 2;
      const float4* wp = (const float4*)(WUs + ((size_t)(w - 256) * 512 + wv * 128) * 4);
      float acc[8];
#pragma unroll
      for (int i = 0; i < 8; ++i) acc[i] = 0.f;
#pragma unroll 4
      for (int kk = 0; kk < 128; ++kk) {
        float2 hv = *(const float2*)(hp + kk * 128);
        float4 wq = wp[kk];
        acc[0] += hv.x*wq.x; acc[1] += hv.y*wq.x;
        acc[2] += hv.x*wq.y; acc[3] += hv.y*wq.y;
        acc[4] += hv.x*wq.z; acc[5] += hv.y*wq.z;
        acc[6] += hv.x*wq.w; acc[7] += hv.y*wq.w;
      }
#pragma unroll
      for (int i = 0; i < 8; ++i) lds[wv * 512 + i * 64 + lane] = acc[i];
      __syncthreads();
      { int b = t & 127, qq = t >> 7, l = b >> 1, bs = b & 1;
        int c0 = (w - 256) * 4;
#pragma unroll
        for (int jj = 0; jj < 2; ++jj) {
          int j = qq + jj * 2;
          float u = 0;
#pragma unroll
          for (int w2 = 0; w2 < 4; ++w2) u += lds[w2 * 512 + (j * 2 + bs) * 64 + l];
          uT[slot * 65536 + (c0 + j) * 128 + b] = u;
        }
      }
      __syncthreads();
    }
  } else if (w < 512) {
    // ---- B: attention for batch b (full 128 s): scores+softmax+context
    const int tB = k - 2;
    if (tB >= 0 && tB <= 126) {
      const int b = w - 384, slot = tB & 1;
      float* uS = lds; float* vS = lds + 512; float* scS = lds + 1024; float* wS = lds + 1152;
      uS[t]       = uT[slot * 65536 + t * 128 + b];
      uS[t + 256] = uT[slot * 65536 + (t + 256) * 128 + b];
      vS[t] = vvec[t]; vS[t + 256] = vvec[t + 256];
      __syncthreads();
      const int h0 = lane * 8;
#pragma unroll 2
      for (int si = 0; si < 32; ++si) {
        int s = wv * 32 + si;
        const float* prow = P + ((size_t)(b * 128 + s)) * 512 + h0;
        float4 p0 = ((const float4*)prow)[0];
        float4 p1 = ((const float4*)prow)[1];
        float val = tanh_(p0.x + uS[h0+0]) * vS[h0+0]
                  + tanh_(p0.y + uS[h0+1]) * vS[h0+1]
                  + tanh_(p0.z + uS[h0+2]) * vS[h0+2]
                  + tanh_(p0.w + uS[h0+3]) * vS[h0+3]
                  + tanh_(p1.x + uS[h0+4]) * vS[h0+4]
                  + tanh_(p1.y + uS[h0+5]) * vS[h0+5]
                  + tanh_(p1.z + uS[h0+6]) * vS[h0+6]
                  + tanh_(p1.w + uS[h0+7]) * vS[h0+7];
#pragma unroll
        for (int off = 32; off; off >>= 1) val += __shfl_xor(val, off);
        if (lane == 0) scS[s] = val;
      }
      __syncthreads();
      if (t < 64) {
        float sc0 = scS[t], sc1 = scS[t + 64];
        float m = fmaxf(sc0, sc1);
#pragma unroll
        for (int off = 32; off; off >>= 1) m = fmaxf(m, __shfl_xor(m, off));
        float e0 = __expf(sc0 - m), e1 = __expf(sc1 - m);
        float zz = e0 + e1;
#pragma unroll
        for (int off = 32; off; off >>= 1) zz += __shfl_xor(zz, off);
        float inv = 1.f / zz;
        wS[t] = e0 * inv; wS[t + 64] = e1 * inv;
      }
      __syncthreads();
      { float acc0 = 0.f, acc1 = 0.f;
        const float* hb = Hst + (size_t)(b * 128) * 512;
#pragma unroll 8
        for (int s = 0; s < 128; ++s) {
          float ws_ = wS[s];
          acc0 += ws_ * hb[(size_t)s * 512 + t];
          acc1 += ws_ * hb[(size_t)s * 512 + t + 256];
        }
        vstack[slot * 131072 + (512 + t) * 128 + b] = acc0;
        vstack[slot * 131072 + (512 + t + 256) * 128 + b] = acc1;
      }
      __syncthreads();
    }
  } else {
    // ---- D: GRU2. 2 c-cols per WG over stacked [h2(t-1); ctx(t)] K=1024,
    //      k-split 4 waves x 256 (waves 0,1: Wh2 part; waves 2,3: ctx part)
    const int tD = k - 3;
    if (tD >= 0 && tD <= 126) {
      const int wd = w - 512, slot = tD & 1, nslot = slot ^ 1;
      const float* vsp = vstack + slot * 131072;
      const float* hp = vsp + (wv * 256) * 128 + lane * 2;
      const float4* wp = (const float4*)(WDs + ((size_t)wd * 1024 + wv * 256) * 8);
      float acc[12];
#pragma unroll
      for (int i = 0; i < 12; ++i) acc[i] = 0.f;
#pragma unroll 4
      for (int kk = 0; kk < 256; ++kk) {
        float2 hv = *(const float2*)(hp + kk * 128);
        float4 wa = wp[kk * 2], wb = wp[kk * 2 + 1];
        acc[0] += hv.x*wa.x; acc[1]  += hv.y*wa.x;
        acc[2] += hv.x*wa.y; acc[3]  += hv.y*wa.y;
        acc[4] += hv.x*wa.z; acc[5]  += hv.y*wa.z;
        acc[6] += hv.x*wa.w; acc[7]  += hv.y*wa.w;
        acc[8] += hv.x*wb.x; acc[9]  += hv.y*wb.x;
        acc[10]+= hv.x*wb.y; acc[11] += hv.y*wb.y;
      }
#pragma unroll
      for (int i = 0; i < 12; ++i) lds[wv * 768 + i * 64 + lane] = acc[i];
      __syncthreads();
      { int b = t & 127, ci = t >> 7, l = b >> 1, bs = b & 1;
        float gr = 0, gz = 0, gnh = 0, gni = 0;
#pragma unroll
        for (int w2 = 0; w2 < 4; ++w2) {
          gr += lds[w2 * 768 + (    ci * 2 + bs) * 64 + l];
          gz += lds[w2 * 768 + (4 + ci * 2 + bs) * 64 + l];
          float g = lds[w2 * 768 + (8 + ci * 2 + bs) * 64 + l];
          if (w2 < 2) gnh += g; else gni += g;
        }
        int c = wd * 2 + ci;
        float x0 = xselT[((tD + 1) * 2) * 128 + b], x1 = xselT[((tD + 1) * 2 + 1) * 128 + b];
        float ir  = A2f[c*2]*x0        + A2f[c*2+1]*x1        + c2f[c];
        float iz  = A2f[(c+512)*2]*x0  + A2f[(c+512)*2+1]*x1  + c2f[c+512];
        float in_ = A2f[(c+1024)*2]*x0 + A2f[(c+1024)*2+1]*x1 + c2f[c+1024] + gni;
        float r = sigm(ir + gr + bh2[c]);
        float z = sigm(iz + gz + bh2[c + 512]);
        float n = tanh_(in_ + r * (gnh + bh2[c + 1024]));
        float hpv = vsp[c * 128 + b];
        vstack[nslot * 131072 + c * 128 + b] = (1.f - z) * n + z * hpv;
      }
      __syncthreads();
    }
  }
}

// ===========================================================================
// persistent cooperative kernel: 130 rounds with grid sync + explicit
// device-scope release/acquire fences (cross-XCD L2 non-coherence, G16).
// ===========================================================================
__global__ void __launch_bounds__(256, 3)
persist_kernel(const float* __restrict__ Hst, const float* __restrict__ bh1,
               const float* __restrict__ vvec, const float* __restrict__ bh2,
               const float* __restrict__ P, const float* __restrict__ WAs,
               const float* __restrict__ WUs, const float* __restrict__ WDs,
               const float* __restrict__ xselT, const float* __restrict__ A1f,
               const float* __restrict__ A2f, const float* __restrict__ c1f,
               const float* __restrict__ c2f,
               float* __restrict__ h1T, float* __restrict__ vstack,
               float* __restrict__ uT)
{
  cg::grid_group grid = cg::this_grid();
  const int w = blockIdx.x, t = threadIdx.x;
  const int wv = __builtin_amdgcn_readfirstlane(t >> 6);
  const int lane = t & 63;
  __shared__ float lds[3072];

  for (int k = 0; k < 130; ++k) {
    round_body(k, w, t, wv, lane, lds, Hst, bh1, vvec, bh2, P, WAs, WUs, WDs,
               xselT, A1f, A2f, c1f, c2f, h1T, vstack, uT);
    __threadfence();   // release: drain + make my writes device-visible
    grid.sync();
    __threadfence();   // acquire: invalidate stale local cache lines
  }
}

// ---- fallback: one round per launch (kernel boundary = sync + coherence)
__global__ void __launch_bounds__(256, 3)
round_kernel(int k, const float* __restrict__ Hst, const float* __restrict__ bh1,
             const float* __restrict__ vvec, const float* __restrict__ bh2,
             const float* __restrict__ P, const float* __restrict__ WAs,
             const float* __restrict__ WUs, const float* __restrict__ WDs,
             const float* __restrict__ xselT, const float* __restrict__ A1f,
             const float* __restrict__ A2f, const float* __restrict__ c1f,
             const float* __restrict__ c2f,
             float* __restrict__ h1T, float* __restrict__ vstack,
             float* __restrict__ uT)
{
  const int w = blockIdx.x, t = threadIdx.x;
  const int wv = __builtin_amdgcn_readfirstlane(t >> 6);
  const int lane = t & 63;
  __shared__ float lds[3072];
  round_body(k, w, t, wv, lane, lds, Hst, bh1, vvec, bh2, P, WAs, WUs, WDs,
             xselT, A1f, A2f, c1f, c2f, h1T, vstack, uT);
}

// ===========================================================================
// epilogue: mu/logvar/z from h2(126) (vstack slot 1, rows 0..511)
// ===========================================================================
__global__ __launch_bounds__(128)
void final_kernel(const float* __restrict__ vstack, const float* __restrict__ eps,
                  const float* __restrict__ W1, const float* __restrict__ b1,
                  const float* __restrict__ W2, const float* __restrict__ b2,
                  float* __restrict__ out)
{
  const int b = blockIdx.x, t = threadIdx.x;
  __shared__ float hS[512];
  const float* h2 = vstack + 131072;
  for (int i = t; i < 512; i += 128) hS[i] = h2[i * 128 + b];
  __syncthreads();
  if (t < 100) {
    const float* w1 = W1 + (size_t)t * 512;
    const float* w2 = W2 + (size_t)t * 512;
    float mu = b1[t], lv = b2[t];
    for (int kk = 0; kk < 512; ++kk) { float h = hS[kk]; mu += h * w1[kk]; lv += h * w2[kk]; }
    float zz = mu + eps[b * 100 + t] * __expf(0.5f * lv);
    out[b * 100 + t] = zz;
    out[12800 + b * 100 + t] = mu;
    out[25600 + b * 100 + t] = lv;
  }
}

// ===========================================================================
extern "C" void kernel_launch(void* const* d_in, const int* in_sizes, int n_in,
                              void* d_out, int out_size, void* d_ws, size_t ws_size,
                              hipStream_t stream)
{
  const float* instance = (const float*)d_in[0];
  const int*   solution = (const int*)d_in[1];
  const float* Hst      = (const float*)d_in[2];
  const float* eps      = (const float*)d_in[3];
  const float* Wr  = (const float*)d_in[4];
  const float* br  = (const float*)d_in[5];
  const float* Wi1 = (const float*)d_in[6];
  const float* Wh1 = (const float*)d_in[7];
  const float* bi1 = (const float*)d_in[8];
  const float* bh1 = (const float*)d_in[9];
  const float* Wa  = (const float*)d_in[10];
  const float* Ua  = (const float*)d_in[11];
  const float* v   = (const float*)d_in[12];
  const float* Wi2 = (const float*)d_in[13];
  const float* Wh2 = (const float*)d_in[14];
  const float* bi2 = (const float*)d_in[15];
  const float* bh2 = (const float*)d_in[16];
  const float* W1  = (const float*)d_in[17];
  const float* b1  = (const float*)d_in[18];
  const float* W2  = (const float*)d_in[19];
  const float* b2  = (const float*)d_in[20];

  float* wsf   = (float*)d_ws;
  float* P     = wsf;                    // 8,388,608
  float* WAs   = P     + 8388608;        // 1,048,576
  float* WUs   = WAs   + 1048576;        //   262,144
  float* WDs   = WUs   + 262144;         // 2,097,152
  float* xselT = WDs   + 2097152;        //    32,768
  float* A1f   = xselT + 32768;          //     3,072
  float* A2f   = A1f   + 3072;           //     3,072
  float* c1f   = A2f   + 3072;           //     1,536
  float* c2f   = c1f   + 1536;           //     1,536
  float* h1T   = c2f   + 1536;           //   131,072
  float* vstack= h1T   + 131072;         //   262,144
  float* uT    = vstack+ 262144;         //   131,072

  prep_kernel<<<dim3(2057), dim3(256), 0, stream>>>(
      instance, solution, Hst, Wr, br, Wi1, bi1, Wh1, Wa, Ua, Wi2, Wh2, bi2,
      P, WAs, WUs, WDs, xselT, A1f, A2f, c1f, c2f, h1T, vstack);

  const float *Hst_ = Hst, *bh1_ = bh1, *v_ = v, *bh2_ = bh2;
  const float *P_ = P, *WAs_ = WAs, *WUs_ = WUs, *WDs_ = WDs;
  const float *xselT_ = xselT, *A1f_ = A1f, *A2f_ = A2f, *c1f_ = c1f, *c2f_ = c2f;
  float *h1T_ = h1T, *vstack_ = vstack, *uT_ = uT;
  void* args[] = {(void*)&Hst_, (void*)&bh1_, (void*)&v_, (void*)&bh2_,
                  (void*)&P_, (void*)&WAs_, (void*)&WUs_, (void*)&WDs_,
                  (void*)&xselT_, (void*)&A1f_, (void*)&A2f_, (void*)&c1f_,
                  (void*)&c2f_, (void*)&h1T_, (void*)&vstack_, (void*)&uT_};
  hipError_t rc = hipLaunchCooperativeKernel((void*)persist_kernel, dim3(768),
                                             dim3(256), args, 0, stream);
  if (rc != hipSuccess) {
    // cooperative launch unavailable -> per-round launches (kernel boundary sync)
    for (int k = 0; k < 130; ++k)
      round_kernel<<<dim3(768), dim3(256), 0, stream>>>(
          k, Hst, bh1, v, bh2, P, WAs, WUs, WDs, xselT, A1f, A2f, c1f, c2f,
          h1T, vstack, uT);
  }

  final_kernel<<<dim3(128), dim3(128), 0, stream>>>(vstack, eps, W1, b1, W2, b2, (float*)d_out);
}